// Round 12
// baseline (202.571 us; speedup 1.0000x reference)
//
#include <hip/hip_runtime.h>
#include <cstdint>

#define N_TOK 2048
#define CDIM  1024
#define NEXP  16
#define TOPK  2
#define HDIM  1024
#define SDIM  2048
#define ESLOT 48
#define ESLOT64 80
#define GU_EXP_BLOCKS (ESLOT * 16)              // 768
#define GU_SH_BLOCKS  (16 * 32)                 // 512
#define GU_NWG (GU_EXP_BLOCKS + GU_SH_BLOCKS)   // 1280
#define DN_EXP_BLOCKS (ESLOT64 * 8)             // 640
#define DN_SH_BLOCKS  (32 * 8)                  // 256
#define DN_NWG (DN_EXP_BLOCKS + DN_SH_BLOCKS)   // 896

typedef __bf16 bf16;
typedef __bf16 bf16x8 __attribute__((ext_vector_type(8)));
typedef float  f32x4  __attribute__((ext_vector_type(4)));
typedef unsigned int u32;
typedef unsigned short u16;

typedef __attribute__((address_space(3))) uint32_t lds_u32_t;
typedef __attribute__((address_space(1))) uint32_t glb_u32_t;

__device__ __forceinline__ void gload16(const void* g, void* l) {
  __builtin_amdgcn_global_load_lds((const glb_u32_t*)(uintptr_t)g,
                                   (lds_u32_t*)(uintptr_t)l, 16, 0, 0);
}
__device__ __forceinline__ float fromb(u16 s) {
  union { float f; u32 u; } z; z.u = ((u32)s) << 16; return z.f;
}
__device__ __forceinline__ int xcd_swz(int bid, int nwg) {
  return (bid & 7) * (nwg >> 3) + (bid >> 3);
}
#define SBAR0() __builtin_amdgcn_sched_barrier(0)
#define WAIT_VM(N) do { asm volatile("s_waitcnt vmcnt(" #N ")" ::: "memory"); \
                        SBAR0(); } while (0)

// ---------------- weight canonicalization ----------------
// one kernel for sgw, suw, sdw (each 2M elements; 1024 blocks each)
__global__ void convert_small3(const float* __restrict__ sgw,
                               const float* __restrict__ suw,
                               const float* __restrict__ sdw,
                               bf16* __restrict__ sgw_b,
                               bf16* __restrict__ suw_b,
                               bf16* __restrict__ sdw_b) {
  const int b = blockIdx.x;
  const float* s; bf16* d;
  if (b < 1024)       { s = sgw; d = sgw_b; }
  else if (b < 2048)  { s = suw; d = suw_b; }
  else                { s = sdw; d = sdw_b; }
  int i = ((b & 1023) * 256 + threadIdx.x) * 8;
  float4 f0 = *(const float4*)(s + i);
  float4 f1 = *(const float4*)(s + i + 4);
  bf16x8 v;
  v[0]=(bf16)f0.x; v[1]=(bf16)f0.y; v[2]=(bf16)f0.z; v[3]=(bf16)f0.w;
  v[4]=(bf16)f1.x; v[5]=(bf16)f1.y; v[6]=(bf16)f1.z; v[7]=(bf16)f1.w;
  *(bf16x8*)(d + i) = v;
}

// transpose-convert: src [E][K][N] fp32 -> dst [E][N][K] bf16 (64x64 tiles)
__global__ __launch_bounds__(256)
void convert_t(const float* __restrict__ src, bf16* __restrict__ dst, int K, int N) {
  __shared__ float ld[64 * 68];
  const int e = blockIdx.z;
  const int n0 = blockIdx.x * 64, k0 = blockIdx.y * 64;
  const float* s = src + (size_t)e * K * N;
  bf16* d = dst + (size_t)e * N * K;
  const int t = threadIdx.x;
  const int kk = t >> 4, c4 = (t & 15) * 4;
#pragma unroll
  for (int q = 0; q < 4; ++q) {
    float4 f = *(const float4*)(s + (size_t)(k0 + kk + q * 16) * N + n0 + c4);
    float* lp = &ld[(kk + q * 16) * 68 + c4];
    lp[0] = f.x; lp[1] = f.y; lp[2] = f.z; lp[3] = f.w;
  }
  __syncthreads();
  const int nn = t >> 2, kc = (t & 3) * 16;
  bf16x8 v0, v1;
#pragma unroll
  for (int j = 0; j < 8; ++j) {
    v0[j] = (bf16)ld[(kc + j) * 68 + nn];
    v1[j] = (bf16)ld[(kc + 8 + j) * 68 + nn];
  }
  bf16* dp = d + (size_t)(n0 + nn) * K + k0 + kc;
  *(bf16x8*)dp = v0;
  *(bf16x8*)(dp + 8) = v1;
}

// ---------------- router (fused x->bf16 conversion) ----------------
__global__ void router_kernel(const float* __restrict__ x,
                              const float* __restrict__ rw,
                              bf16* __restrict__ xb,
                              int* __restrict__ sel,
                              float* __restrict__ gatew) {
  int n = blockIdx.x;
  int lane = threadIdx.x;
  const float* xr = x + (size_t)n * CDIM;
  float xv[16];
#pragma unroll
  for (int q = 0; q < 4; ++q) {
    float4 f = *(const float4*)(xr + lane * 16 + q * 4);
    xv[q * 4 + 0] = f.x; xv[q * 4 + 1] = f.y; xv[q * 4 + 2] = f.z; xv[q * 4 + 3] = f.w;
  }
  bf16x8 v0, v1;
#pragma unroll
  for (int j = 0; j < 8; ++j) { v0[j] = (bf16)xv[j]; v1[j] = (bf16)xv[8 + j]; }
  bf16* xo = xb + (size_t)n * CDIM + lane * 16;
  *(bf16x8*)xo = v0;
  *(bf16x8*)(xo + 8) = v1;
  float acc[NEXP];
#pragma unroll
  for (int e = 0; e < NEXP; ++e) {
    float a = 0.f;
    const float* rwe = rw + e * CDIM + lane * 16;
#pragma unroll
    for (int j = 0; j < 16; ++j) a += xv[j] * rwe[j];
    acc[e] = a;
  }
#pragma unroll
  for (int off = 32; off > 0; off >>= 1) {
#pragma unroll
    for (int e = 0; e < NEXP; ++e) acc[e] += __shfl_xor(acc[e], off, 64);
  }
  if (lane == 0) {
    int i0 = 0; float v0_ = acc[0];
#pragma unroll
    for (int e = 1; e < NEXP; ++e) if (acc[e] > v0_) { v0_ = acc[e]; i0 = e; }
    int i1 = (i0 == 0) ? 1 : 0; float v1_ = acc[i1];
#pragma unroll
    for (int e = 0; e < NEXP; ++e) if (e != i0 && acc[e] > v1_) { v1_ = acc[e]; i1 = e; }
    sel[2 * n] = i0; sel[2 * n + 1] = i1;
    gatew[2 * n]     = 1.f / (1.f + expf(-v0_));
    gatew[2 * n + 1] = 1.f / (1.f + expf(-v1_));
  }
}

// scan + scatter fused (1 block). Entry order within an expert is
// non-deterministic but the final output bits are permutation-invariant.
__global__ void scan_scatter(const int* __restrict__ sel,
                             const float* __restrict__ gatew,
                             int* __restrict__ counts,
                             int* __restrict__ offsets,
                             int* __restrict__ tab128,
                             int* __restrict__ tab64,
                             int* __restrict__ ntiles,
                             int* __restrict__ entry_token,
                             float* __restrict__ entry_gate,
                             int* __restrict__ entry_pos) {
  __shared__ int hist[NEXP], cur[NEXP];
  const int t = threadIdx.x;
  if (t < NEXP) hist[t] = 0;
  __syncthreads();
  for (int i = t; i < N_TOK * TOPK; i += 256) atomicAdd(&hist[sel[i]], 1);
  __syncthreads();
  if (t == 0) {
    int s = 0, a = 0, b = 0;
    for (int e = 0; e < NEXP; ++e) {
      int c = hist[e];
      counts[e] = c; offsets[e] = s; cur[e] = s;
      for (int m0 = 0; m0 < c; m0 += 128) tab128[a++] = (e << 16) | m0;
      for (int m0 = 0; m0 < c; m0 += 64)  tab64[b++]  = (e << 16) | m0;
      s += c;
    }
    ntiles[0] = a; ntiles[1] = b;
  }
  __syncthreads();
  for (int i = t; i < N_TOK * TOPK; i += 256) {
    int e = sel[i];
    int pos = atomicAdd(&cur[e], 1);
    entry_token[pos] = i >> 1;
    entry_gate[pos] = gatew[i];
    entry_pos[i] = pos;
  }
}

// ================= GU: gate+up GEMM, BK=32, 4 blocks/CU ======================
// Tile 128m x 64h dual-B. A 2-buf (1-ahead), B 3-buf (2-ahead), vmcnt(2).
// LDS 4-slot swizzle f(r)=(r>>1)&3 (2-way bank alias = free).
__global__ __launch_bounds__(256, 4)
void gu8(const bf16* __restrict__ xb,
         const bf16* __restrict__ guwb,    // [E][2048][1024]
         const bf16* __restrict__ sgwb,
         const bf16* __restrict__ suwb,
         bf16* __restrict__ h_exp,
         bf16* __restrict__ h_sh,
         const int* __restrict__ counts,
         const int* __restrict__ offsets,
         const int* __restrict__ entry_token,
         const int* __restrict__ tab128,
         const int* __restrict__ ntiles) {
  __shared__ __align__(16) bf16 sA[2 * 4096];   // 2 x (128r x 32k) = 8 KB each
  __shared__ __align__(16) bf16 sBg[3 * 2048];  // 3 x (64r x 32k) = 4 KB each
  __shared__ __align__(16) bf16 sBu[3 * 2048];

  const int bid = xcd_swz(blockIdx.x, GU_NWG);
  const int t = threadIdx.x;
  const bool is_exp = bid < GU_EXP_BLOCKS;
  const int wid = t >> 6, lane = t & 63;

  int n0, mguard;
  bf16* hbase; int hstride;
  const bf16 *Bg, *Bu;
  const int prow = t >> 2;      // staging row within 64-row group
  const int ppos = t & 3;       // 16B slot within row
  const bf16* asrc[2];

  if (is_exp) {
    const int slot = bid >> 4;
    if (slot >= ntiles[0]) return;
    const int packed = tab128[slot];
    const int e = packed >> 16;
    const int m0 = packed & 0xffff;
    const int cnt = counts[e];
    const int base = offsets[e];
    n0 = (bid & 15) * 64;
    mguard = cnt - m0;
#pragma unroll
    for (int i = 0; i < 2; ++i) {
      const int row = i * 64 + prow;
      int r = m0 + row;
      int tok = entry_token[base + ((r < cnt) ? r : (cnt - 1))];
      const int c = ppos ^ ((row >> 1) & 3);
      asrc[i] = xb + (size_t)tok * CDIM + c * 8;
    }
    const bf16* we = guwb + (size_t)e * (2 * HDIM) * CDIM;
    Bg = we + (size_t)n0 * CDIM;
    Bu = we + (size_t)(HDIM + n0) * CDIM;
    hbase = h_exp + (size_t)(base + m0) * HDIM + n0;
    hstride = HDIM;
  } else {
    const int sid = bid - GU_EXP_BLOCKS;
    const int m0 = (sid >> 5) * 128;
    n0 = (sid & 31) * 64;
    mguard = 128;
#pragma unroll
    for (int i = 0; i < 2; ++i) {
      const int row = i * 64 + prow;
      const int c = ppos ^ ((row >> 1) & 3);
      asrc[i] = xb + (size_t)(m0 + row) * CDIM + c * 8;
    }
    Bg = sgwb + (size_t)n0 * CDIM;
    Bu = suwb + (size_t)n0 * CDIM;
    hbase = h_sh + (size_t)m0 * SDIM + n0;
    hstride = SDIM;
  }

  const int bc = ppos ^ ((prow >> 1) & 3);
  const bf16* bg0 = Bg + (size_t)prow * CDIM + bc * 8;
  const bf16* bu0 = Bu + (size_t)prow * CDIM + bc * 8;
  const int pdst = t * 8;   // element offset within a 64-row (2048-elem) group

#define ISSUE_A(k_, ab_)                                                      \
  do {                                                                        \
    _Pragma("unroll")                                                         \
    for (int i = 0; i < 2; ++i)                                               \
      gload16(asrc[i] + (k_), &sA[(ab_) * 4096 + i * 2048 + pdst]);           \
  } while (0)
#define ISSUE_B(k_, bo_)                                                      \
  do {                                                                        \
    gload16(bg0 + (k_), &sBg[(bo_) + pdst]);                                  \
    gload16(bu0 + (k_), &sBu[(bo_) + pdst]);                                  \
  } while (0)

  const int wr = (wid >> 1) * 64, wc = (wid & 1) * 32;
  const int lrow = lane & 15, grp = lane >> 4;

  f32x4 ag[4][2], au[4][2];
#pragma unroll
  for (int m = 0; m < 4; ++m)
#pragma unroll
    for (int n = 0; n < 2; ++n)
#pragma unroll
      for (int i = 0; i < 4; ++i) { ag[m][n][i] = 0.f; au[m][n][i] = 0.f; }

#define COMPUTE(ab_, bo_)                                                     \
  do {                                                                        \
    bf16x8 av[4], bg[2], bu[2];                                               \
    _Pragma("unroll")                                                         \
    for (int m = 0; m < 4; ++m) {                                             \
      const int r = wr + m * 16 + lrow;                                       \
      av[m] = *(const bf16x8*)&sA[(ab_) * 4096 + r * 32 +                     \
                                  ((grp ^ ((r >> 1) & 3)) << 3)];             \
    }                                                                         \
    _Pragma("unroll")                                                         \
    for (int n = 0; n < 2; ++n) {                                             \
      const int r = wc + n * 16 + lrow;                                       \
      const int so = r * 32 + ((grp ^ ((r >> 1) & 3)) << 3);                  \
      bg[n] = *(const bf16x8*)&sBg[(bo_) + so];                               \
      bu[n] = *(const bf16x8*)&sBu[(bo_) + so];                               \
    }                                                                         \
    _Pragma("unroll")                                                         \
    for (int m = 0; m < 4; ++m)                                               \
      _Pragma("unroll")                                                       \
      for (int n = 0; n < 2; ++n) {                                           \
        ag[m][n] = __builtin_amdgcn_mfma_f32_16x16x32_bf16(av[m], bg[n], ag[m][n], 0, 0, 0); \
        au[m][n] = __builtin_amdgcn_mfma_f32_16x16x32_bf16(av[m], bu[n], au[m][n], 0, 0, 0); \
      }                                                                       \
  } while (0)

  // prologue: A(0),B(0),B(1); wait so only B(1) (2 loads) stays in flight
  ISSUE_A(0, 0);
  ISSUE_B(0, 0);
  SBAR0();
  ISSUE_B(32, 2048);
  SBAR0();
  WAIT_VM(2);
  __builtin_amdgcn_s_barrier();

  int bb0 = 0, bb1 = 2048, bb2 = 4096;
  for (int k = 0; k < 30; ++k) {       // 32 K-steps total
    ISSUE_A((k + 1) * 32, (k + 1) & 1);
    SBAR0();
    ISSUE_B((k + 2) * 32, bb2);
    SBAR0();
    COMPUTE(k & 1, bb0);
    WAIT_VM(2);                        // A(k+1)+B(k+1) done; B(k+2) in flight
    __builtin_amdgcn_s_barrier();
    int tmp = bb0; bb0 = bb1; bb1 = bb2; bb2 = tmp;
  }
  ISSUE_A(31 * 32, 1);
  SBAR0();
  COMPUTE(0, bb0);
  WAIT_VM(0);
  __builtin_amdgcn_s_barrier();
  { int tmp = bb0; bb0 = bb1; bb1 = bb2; bb2 = tmp; }
  COMPUTE(1, bb0);
#undef ISSUE_A
#undef ISSUE_B
#undef COMPUTE

  // SwiGLU epilogue (C/D: col=lane&15, row=grp*4+i)
#pragma unroll
  for (int m = 0; m < 4; ++m) {
#pragma unroll
    for (int i = 0; i < 4; ++i) {
      const int rl = wr + m * 16 + grp * 4 + i;
      if (rl >= mguard) continue;
      bf16* orow = hbase + (size_t)rl * hstride;
#pragma unroll
      for (int n = 0; n < 2; ++n) {
        const float g = ag[m][n][i];
        const float u = au[m][n][i];
        orow[wc + n * 16 + lrow] = (bf16)(g * u * __builtin_amdgcn_rcpf(1.f + __expf(-g)));
      }
    }
  }
}

// ================= DOWN GEMM, BK=32, 5 blocks/CU ==============================
// Tile 64m x 128n. A 2-buf, B 3-buf (2-ahead), vmcnt(2).
__global__ __launch_bounds__(256, 4)
void dn8(const bf16* __restrict__ h_exp,
         const bf16* __restrict__ h_sh,
         const bf16* __restrict__ dwb,    // [E][1024][1024]
         const bf16* __restrict__ sdwb,   // [1024][2048]
         const float* __restrict__ entry_gate,
         bf16* __restrict__ out_e,
         float* __restrict__ out,
         const int* __restrict__ counts,
         const int* __restrict__ offsets,
         const int* __restrict__ tab64,
         const int* __restrict__ ntiles) {
  __shared__ __align__(16) bf16 sA[2 * 2048];   // 2 x (64r x 32k) = 4 KB each
  __shared__ __align__(16) bf16 sB[3 * 4096];   // 3 x (128r x 32k) = 8 KB each

  const int bid = xcd_swz(blockIdx.x, DN_NWG);
  const int t = threadIdx.x;
  const bool is_exp = bid < DN_EXP_BLOCKS;
  const int wid = t >> 6, lane = t & 63;

  int n0, mguard, K, rowbase, NK;
  const bf16* Ab;
  const bf16* Bb;

  if (is_exp) {
    const int slot = bid >> 3;
    if (slot >= ntiles[1]) return;
    const int packed = tab64[slot];
    const int e = packed >> 16;
    const int m0 = packed & 0xffff;
    const int cnt = counts[e];
    n0 = (bid & 7) * 128;
    mguard = cnt - m0;
    K = HDIM; NK = HDIM / 32;
    rowbase = offsets[e] + m0;
    Ab = h_exp;
    Bb = dwb + (size_t)e * CDIM * HDIM + (size_t)n0 * HDIM;
  } else {
    const int sid = bid - DN_EXP_BLOCKS;
    const int m0 = (sid >> 3) * 64;
    n0 = (sid & 7) * 128;
    mguard = 64;
    K = SDIM; NK = SDIM / 32;
    rowbase = m0;
    Ab = h_sh;
    Bb = sdwb + (size_t)n0 * SDIM;
  }

  const int prow = t >> 2;
  const int ppos = t & 3;
  // A: 1 instr covers 64 rows
  int arg = rowbase + prow;
  if (is_exp && arg > N_TOK * TOPK - 1) arg = N_TOK * TOPK - 1;
  const int ac = ppos ^ ((prow >> 1) & 3);
  const bf16* asrc = Ab + (size_t)arg * K + ac * 8;
  // B: 2 instrs cover 128 rows
  const bf16* bsrc[2];
#pragma unroll
  for (int i = 0; i < 2; ++i) {
    const int row = i * 64 + prow;
    const int c = ppos ^ ((row >> 1) & 3);
    bsrc[i] = Bb + (size_t)row * K + c * 8;
  }
  const int pdst = t * 8;

#define ISSUE_A(k_, ab_)                                                      \
  gload16(asrc + (k_), &sA[(ab_) * 2048 + pdst])
#define ISSUE_B(k_, bo_)                                                      \
  do {                                                                        \
    _Pragma("unroll")                                                         \
    for (int i = 0; i < 2; ++i)                                               \
      gload16(bsrc[i] + (k_), &sB[(bo_) + i * 2048 + pdst]);                  \
  } while (0)

  const int wr = (wid >> 1) * 32, wc = (wid & 1) * 64;
  const int lrow = lane & 15, grp = lane >> 4;

  f32x4 acc[2][4];
#pragma unroll
  for (int m = 0; m < 2; ++m)
#pragma unroll
    for (int n = 0; n < 4; ++n)
#pragma unroll
      for (int i = 0; i < 4; ++i) acc[m][n][i] = 0.f;

#define COMPUTE(ab_, bo_)                                                     \
  do {                                                                        \
    bf16x8 av[2], bv[4];                                                      \
    _Pragma("unroll")                                                         \
    for (int m = 0; m < 2; ++m) {                                             \
      const int r = wr + m * 16 + lrow;                                       \
      av[m] = *(const bf16x8*)&sA[(ab_) * 2048 + r * 32 +                     \
                                  ((grp ^ ((r >> 1) & 3)) << 3)];             \
    }                                                                         \
    _Pragma("unroll")                                                         \
    for (int n = 0; n < 4; ++n) {                                             \
      const int r = wc + n * 16 + lrow;                                       \
      bv[n] = *(const bf16x8*)&sB[(bo_) + r * 32 +                            \
                                  ((grp ^ ((r >> 1) & 3)) << 3)];             \
    }                                                                         \
    _Pragma("unroll")                                                         \
    for (int m = 0; m < 2; ++m)                                               \
      _Pragma("unroll")                                                       \
      for (int n = 0; n < 4; ++n)                                             \
        acc[m][n] = __builtin_amdgcn_mfma_f32_16x16x32_bf16(av[m], bv[n], acc[m][n], 0, 0, 0); \
  } while (0)

  ISSUE_A(0, 0);
  ISSUE_B(0, 0);
  SBAR0();
  ISSUE_B(32, 4096);
  SBAR0();
  WAIT_VM(2);
  __builtin_amdgcn_s_barrier();

  int bb0 = 0, bb1 = 4096, bb2 = 8192;
  for (int k = 0; k < NK - 2; ++k) {
    ISSUE_A((k + 1) * 32, (k + 1) & 1);
    SBAR0();
    ISSUE_B((k + 2) * 32, bb2);
    SBAR0();
    COMPUTE(k & 1, bb0);
    WAIT_VM(2);
    __builtin_amdgcn_s_barrier();
    int tmp = bb0; bb0 = bb1; bb1 = bb2; bb2 = tmp;
  }
  ISSUE_A((NK - 1) * 32, (NK - 1) & 1);
  SBAR0();
  COMPUTE((NK - 2) & 1, bb0);
  WAIT_VM(0);
  __builtin_amdgcn_s_barrier();
  { int tmp = bb0; bb0 = bb1; bb1 = bb2; bb2 = tmp; }
  COMPUTE((NK - 1) & 1, bb0);
#undef ISSUE_A
#undef ISSUE_B
#undef COMPUTE

#pragma unroll
  for (int m = 0; m < 2; ++m) {
#pragma unroll
    for (int i = 0; i < 4; ++i) {
      const int rl = wr + m * 16 + grp * 4 + i;
      if (rl >= mguard) continue;
      if (is_exp) {
        const int row = rowbase + rl;
        const float scl = entry_gate[row];
        bf16* orow = out_e + (size_t)row * CDIM + n0;
#pragma unroll
        for (int n = 0; n < 4; ++n)
          orow[wc + n * 16 + lrow] = (bf16)(acc[m][n][i] * scl);
      } else {
        float* orow = out + (size_t)(rowbase + rl) * CDIM + n0;
#pragma unroll
        for (int n = 0; n < 4; ++n)
          orow[wc + n * 16 + lrow] = acc[m][n][i];
      }
    }
  }
}

// ---------------- combine ----------------
__global__ void combine_kernel(float* __restrict__ out,
                               const bf16* __restrict__ out_e,
                               const int* __restrict__ entry_pos) {
  int tid = blockIdx.x * blockDim.x + threadIdx.x;
  int n = tid >> 8;
  int c4 = tid & 255;
  int p0 = entry_pos[2 * n];
  int p1 = entry_pos[2 * n + 1];
  float4 v = ((const float4*)out)[tid];
  ushort4 a = *(const ushort4*)((const u16*)out_e + (size_t)p0 * CDIM + c4 * 4);
  ushort4 b = *(const ushort4*)((const u16*)out_e + (size_t)p1 * CDIM + c4 * 4);
  v.x += fromb(a.x) + fromb(b.x);
  v.y += fromb(a.y) + fromb(b.y);
  v.z += fromb(a.z) + fromb(b.z);
  v.w += fromb(a.w) + fromb(b.w);
  ((float4*)out)[tid] = v;
}

extern "C" void kernel_launch(void* const* d_in, const int* in_sizes, int n_in,
                              void* d_out, int out_size, void* d_ws, size_t ws_size,
                              hipStream_t stream) {
  const float* x   = (const float*)d_in[0];
  const float* rw  = (const float*)d_in[1];
  const float* guw = (const float*)d_in[2];
  const float* dw  = (const float*)d_in[3];
  const float* sgw = (const float*)d_in[4];
  const float* suw = (const float*)d_in[5];
  const float* sdw = (const float*)d_in[6];
  float* out = (float*)d_out;
  char* ws = (char*)d_ws;
  const size_t MB = 1048576;

  int*   sel         = (int*)(ws + 0);
  float* gatew       = (float*)(ws + 16384);
  int*   counts      = (int*)(ws + 32768);
  int*   offsets     = (int*)(ws + 32832);
  int*   ntiles      = (int*)(ws + 32960);
  int*   tab128      = (int*)(ws + 33024);
  int*   tab64       = (int*)(ws + 33280);
  int*   entry_token = (int*)(ws + 33664);
  float* entry_gate  = (float*)(ws + 50048);
  int*   entry_pos   = (int*)(ws + 66432);

  bf16* xb    = (bf16*)(ws + 82816);                 // 4 MB
  bf16* h_exp = (bf16*)(ws + 82816 + 4 * MB);        // 8 MB
  bf16* h_sh  = (bf16*)(ws + 82816 + 12 * MB);       // 8 MB
  bf16* sgw_b = (bf16*)(ws + 82816 + 20 * MB);       // 4 MB
  bf16* suw_b = (bf16*)(ws + 82816 + 24 * MB);       // 4 MB
  bf16* Wbig  = (bf16*)(ws + 82816 + 28 * MB);       // 64 MB: guw_b, then dw_b
  bf16* sdw_b = (bf16*)(ws + 82816 + 92 * MB);       // 4 MB (peak ~96 MB)
  bf16* out_e = sgw_b;                               // alias (dead after gu8)

  // routing + fused x conversion
  router_kernel<<<N_TOK, 64, 0, stream>>>(x, rw, xb, sel, gatew);
  scan_scatter<<<1, 256, 0, stream>>>(sel, gatew, counts, offsets, tab128, tab64,
                                      ntiles, entry_token, entry_gate, entry_pos);

  // canonicalize weights (gu-side + all small)
  convert_t<<<dim3(32, 16, NEXP), 256, 0, stream>>>(guw, Wbig, CDIM, 2 * HDIM);
  convert_small3<<<3072, 256, 0, stream>>>(sgw, suw, sdw, sgw_b, suw_b, sdw_b);

  // gate+up + SwiGLU (expert + shared)
  gu8<<<GU_NWG, 256, 0, stream>>>(xb, Wbig, sgw_b, suw_b, h_exp, h_sh,
                                  counts, offsets, entry_token, tab128, ntiles);

  // canonicalize dn-side expert weights (into Wbig, freed by gu8)
  convert_t<<<dim3(16, 16, NEXP), 256, 0, stream>>>(dw, Wbig, HDIM, CDIM);

  // down (expert + shared)
  dn8<<<DN_NWG, 256, 0, stream>>>(h_exp, h_sh, Wbig, sdw_b, entry_gate, out_e, out,
                                  counts, offsets, tab64, ntiles);

  // add gated expert contributions
  combine_kernel<<<(N_TOK * CDIM / 4) / 256, 256, 0, stream>>>(out, out_e, entry_pos);
}

// Round 13
// 177.982 us; speedup vs baseline: 1.1382x; 1.1382x over previous
//
#include <hip/hip_runtime.h>
#include <cstdint>

#define N_TOK 2048
#define CDIM  1024
#define NEXP  16
#define TOPK  2
#define HDIM  1024
#define SDIM  2048
#define ESLOT 48
#define GU_EXP_BLOCKS (ESLOT * 16)              // 768 (16 n-tiles of 64)
#define GU_SH_BLOCKS  (16 * 32)                 // 512
#define GU_NWG (GU_EXP_BLOCKS + GU_SH_BLOCKS)   // 1280
#define DN_EXP_BLOCKS (ESLOT * 8)               // 384 (8 n-tiles of 128)
#define DN_SH_BLOCKS  (16 * 8)                  // 128
#define DN_NWG (DN_EXP_BLOCKS + DN_SH_BLOCKS)   // 512

typedef __bf16 bf16;
typedef __bf16 bf16x8 __attribute__((ext_vector_type(8)));
typedef float  f32x4  __attribute__((ext_vector_type(4)));
typedef unsigned int u32;
typedef unsigned short u16;

typedef __attribute__((address_space(3))) uint32_t lds_u32_t;
typedef __attribute__((address_space(1))) uint32_t glb_u32_t;

__device__ __forceinline__ void gload16(const void* g, void* l) {
  __builtin_amdgcn_global_load_lds((const glb_u32_t*)(uintptr_t)g,
                                   (lds_u32_t*)(uintptr_t)l, 16, 0, 0);
}
__device__ __forceinline__ float fromb(u16 s) {
  union { float f; u32 u; } z; z.u = ((u32)s) << 16; return z.f;
}
__device__ __forceinline__ int xcd_swz(int bid, int nwg) {
  return (bid & 7) * (nwg >> 3) + (bid >> 3);
}
#define SBAR0() __builtin_amdgcn_sched_barrier(0)
#define WAIT_VM(N) do { asm volatile("s_waitcnt vmcnt(" #N ")" ::: "memory"); \
                        SBAR0(); } while (0)

// ---------------- weight canonicalization ----------------
__global__ void convert_small3(const float* __restrict__ sgw,
                               const float* __restrict__ suw,
                               const float* __restrict__ sdw,
                               bf16* __restrict__ sgw_b,
                               bf16* __restrict__ suw_b,
                               bf16* __restrict__ sdw_b) {
  const int b = blockIdx.x;
  const float* s; bf16* d;
  if (b < 1024)       { s = sgw; d = sgw_b; }
  else if (b < 2048)  { s = suw; d = suw_b; }
  else                { s = sdw; d = sdw_b; }
  int i = ((b & 1023) * 256 + threadIdx.x) * 8;
  float4 f0 = *(const float4*)(s + i);
  float4 f1 = *(const float4*)(s + i + 4);
  bf16x8 v;
  v[0]=(bf16)f0.x; v[1]=(bf16)f0.y; v[2]=(bf16)f0.z; v[3]=(bf16)f0.w;
  v[4]=(bf16)f1.x; v[5]=(bf16)f1.y; v[6]=(bf16)f1.z; v[7]=(bf16)f1.w;
  *(bf16x8*)(d + i) = v;
}

// transpose-convert: src [E][K][N] fp32 -> dst [E][N][K] bf16 (64x64 tiles)
__global__ __launch_bounds__(256)
void convert_t(const float* __restrict__ src, bf16* __restrict__ dst, int K, int N) {
  __shared__ float ld[64 * 68];
  const int e = blockIdx.z;
  const int n0 = blockIdx.x * 64, k0 = blockIdx.y * 64;
  const float* s = src + (size_t)e * K * N;
  bf16* d = dst + (size_t)e * N * K;
  const int t = threadIdx.x;
  const int kk = t >> 4, c4 = (t & 15) * 4;
#pragma unroll
  for (int q = 0; q < 4; ++q) {
    float4 f = *(const float4*)(s + (size_t)(k0 + kk + q * 16) * N + n0 + c4);
    float* lp = &ld[(kk + q * 16) * 68 + c4];
    lp[0] = f.x; lp[1] = f.y; lp[2] = f.z; lp[3] = f.w;
  }
  __syncthreads();
  const int nn = t >> 2, kc = (t & 3) * 16;
  bf16x8 v0, v1;
#pragma unroll
  for (int j = 0; j < 8; ++j) {
    v0[j] = (bf16)ld[(kc + j) * 68 + nn];
    v1[j] = (bf16)ld[(kc + 8 + j) * 68 + nn];
  }
  bf16* dp = d + (size_t)(n0 + nn) * K + k0 + kc;
  *(bf16x8*)dp = v0;
  *(bf16x8*)(dp + 8) = v1;
}

// ---------------- router (fused x->bf16 conversion) ----------------
__global__ void router_kernel(const float* __restrict__ x,
                              const float* __restrict__ rw,
                              bf16* __restrict__ xb,
                              int* __restrict__ sel,
                              float* __restrict__ gatew) {
  int n = blockIdx.x;
  int lane = threadIdx.x;
  const float* xr = x + (size_t)n * CDIM;
  float xv[16];
#pragma unroll
  for (int q = 0; q < 4; ++q) {
    float4 f = *(const float4*)(xr + lane * 16 + q * 4);
    xv[q * 4 + 0] = f.x; xv[q * 4 + 1] = f.y; xv[q * 4 + 2] = f.z; xv[q * 4 + 3] = f.w;
  }
  bf16x8 v0, v1;
#pragma unroll
  for (int j = 0; j < 8; ++j) { v0[j] = (bf16)xv[j]; v1[j] = (bf16)xv[8 + j]; }
  bf16* xo = xb + (size_t)n * CDIM + lane * 16;
  *(bf16x8*)xo = v0;
  *(bf16x8*)(xo + 8) = v1;
  float acc[NEXP];
#pragma unroll
  for (int e = 0; e < NEXP; ++e) {
    float a = 0.f;
    const float* rwe = rw + e * CDIM + lane * 16;
#pragma unroll
    for (int j = 0; j < 16; ++j) a += xv[j] * rwe[j];
    acc[e] = a;
  }
#pragma unroll
  for (int off = 32; off > 0; off >>= 1) {
#pragma unroll
    for (int e = 0; e < NEXP; ++e) acc[e] += __shfl_xor(acc[e], off, 64);
  }
  if (lane == 0) {
    int i0 = 0; float v0_ = acc[0];
#pragma unroll
    for (int e = 1; e < NEXP; ++e) if (acc[e] > v0_) { v0_ = acc[e]; i0 = e; }
    int i1 = (i0 == 0) ? 1 : 0; float v1_ = acc[i1];
#pragma unroll
    for (int e = 0; e < NEXP; ++e) if (e != i0 && acc[e] > v1_) { v1_ = acc[e]; i1 = e; }
    sel[2 * n] = i0; sel[2 * n + 1] = i1;
    gatew[2 * n]     = 1.f / (1.f + expf(-v0_));
    gatew[2 * n + 1] = 1.f / (1.f + expf(-v1_));
  }
}

// scan + scatter fused (1 block)
__global__ void scan_scatter(const int* __restrict__ sel,
                             const float* __restrict__ gatew,
                             int* __restrict__ counts,
                             int* __restrict__ offsets,
                             int* __restrict__ tab128,
                             int* __restrict__ ntiles,
                             int* __restrict__ entry_token,
                             float* __restrict__ entry_gate,
                             int* __restrict__ entry_pos) {
  __shared__ int hist[NEXP], cur[NEXP];
  const int t = threadIdx.x;
  if (t < NEXP) hist[t] = 0;
  __syncthreads();
  for (int i = t; i < N_TOK * TOPK; i += 256) atomicAdd(&hist[sel[i]], 1);
  __syncthreads();
  if (t == 0) {
    int s = 0, a = 0;
    for (int e = 0; e < NEXP; ++e) {
      int c = hist[e];
      counts[e] = c; offsets[e] = s; cur[e] = s;
      for (int m0 = 0; m0 < c; m0 += 128) tab128[a++] = (e << 16) | m0;
      s += c;
    }
    ntiles[0] = a;
  }
  __syncthreads();
  for (int i = t; i < N_TOK * TOPK; i += 256) {
    int e = sel[i];
    int pos = atomicAdd(&cur[e], 1);
    entry_token[pos] = i >> 1;
    entry_gate[pos] = gatew[i];
    entry_pos[i] = pos;
  }
}

// ================= GU: gate+up GEMM, 512 threads (8 waves), BK=64 ============
// Tile 128m x 64h dual-B. A 2-buf (1-ahead), B 3-buf (2-ahead), vmcnt(2).
// Waves: 4m x 2n; each wave 32m x 32h (dual). B staged panel-split (t<256 gate).
__global__ __launch_bounds__(512, 2)
void gu9(const bf16* __restrict__ xb,
         const bf16* __restrict__ guwb,    // [E][2048][1024]
         const bf16* __restrict__ sgwb,
         const bf16* __restrict__ suwb,
         bf16* __restrict__ h_exp,
         bf16* __restrict__ h_sh,
         const int* __restrict__ counts,
         const int* __restrict__ offsets,
         const int* __restrict__ entry_token,
         const int* __restrict__ tab128,
         const int* __restrict__ ntiles) {
  __shared__ __align__(16) bf16 sA[2 * 8192];    // 2 x 128x64 (32 KB)
  __shared__ __align__(16) bf16 sBg[3 * 4096];   // 3 x 64x64 (24 KB)
  __shared__ __align__(16) bf16 sBu[3 * 4096];   // 24 KB -> 80 KB total

  const int bid = xcd_swz(blockIdx.x, GU_NWG);
  const int t = threadIdx.x;
  const bool is_exp = bid < GU_EXP_BLOCKS;
  const int wid = t >> 6, lane = t & 63;

  int n0, mguard;
  bf16* hbase; int hstride;
  const bf16 *Bg, *Bu;
  const int arow = t >> 3;              // 0..63 (A staging row within group)
  const int sc = (t & 7) ^ (arow & 7);  // A content chunk (row&7 invariant +64)
  const bf16* asrc[2];

  if (is_exp) {
    const int slot = bid >> 4;
    if (slot >= ntiles[0]) return;
    const int packed = tab128[slot];
    const int e = packed >> 16;
    const int m0 = packed & 0xffff;
    const int cnt = counts[e];
    const int base = offsets[e];
    n0 = (bid & 15) * 64;
    mguard = cnt - m0;
#pragma unroll
    for (int i = 0; i < 2; ++i) {
      int r = m0 + i * 64 + arow;
      int tok = entry_token[base + ((r < cnt) ? r : (cnt - 1))];
      asrc[i] = xb + (size_t)tok * CDIM + sc * 8;
    }
    const bf16* we = guwb + (size_t)e * (2 * HDIM) * CDIM;
    Bg = we + (size_t)n0 * CDIM;
    Bu = we + (size_t)(HDIM + n0) * CDIM;
    hbase = h_exp + (size_t)(base + m0) * HDIM + n0;
    hstride = HDIM;
  } else {
    const int sid = bid - GU_EXP_BLOCKS;
    const int m0 = (sid >> 5) * 128;
    n0 = (sid & 31) * 64;
    mguard = 128;
#pragma unroll
    for (int i = 0; i < 2; ++i)
      asrc[i] = xb + (size_t)(m0 + i * 64 + arow) * CDIM + sc * 8;
    Bg = sgwb + (size_t)n0 * CDIM;
    Bu = suwb + (size_t)n0 * CDIM;
    hbase = h_sh + (size_t)m0 * SDIM + n0;
    hstride = SDIM;
  }

  // B staging: threads 0-255 stage gate, 256-511 stage up. 2 loads each.
  const int th = t & 255;
  bf16* bdst = (t >= 256) ? sBu : sBg;
  const bf16* Bp = (t >= 256) ? Bu : Bg;
  const bf16* bsrc[2];
#pragma unroll
  for (int i = 0; i < 2; ++i) {
    const int row = i * 32 + (th >> 3);
    const int c = (th & 7) ^ (row & 7);
    bsrc[i] = Bp + (size_t)row * CDIM + c * 8;
  }
  const int adst = t * 8;     // A dest within 64-row group (+ i*4096)
  const int bdoff = th * 8;   // B dest within 32-row group (+ i*2048)

#define ISSUE_A(k_, ab_)                                                      \
  do {                                                                        \
    _Pragma("unroll")                                                         \
    for (int i = 0; i < 2; ++i)                                               \
      gload16(asrc[i] + (k_), &sA[(ab_) * 8192 + i * 4096 + adst]);           \
  } while (0)
#define ISSUE_B(k_, bo_)                                                      \
  do {                                                                        \
    _Pragma("unroll")                                                         \
    for (int i = 0; i < 2; ++i)                                               \
      gload16(bsrc[i] + (k_), &bdst[(bo_) + i * 2048 + bdoff]);               \
  } while (0)

  const int wr = (wid >> 1) * 32, wc = (wid & 1) * 32;
  const int lrow = lane & 15, grp = lane >> 4;

  f32x4 ag[2][2], au[2][2];
#pragma unroll
  for (int m = 0; m < 2; ++m)
#pragma unroll
    for (int n = 0; n < 2; ++n)
#pragma unroll
      for (int i = 0; i < 4; ++i) { ag[m][n][i] = 0.f; au[m][n][i] = 0.f; }

#define COMPUTE(ab_, bo_)                                                     \
  do {                                                                        \
    _Pragma("unroll")                                                         \
    for (int ks = 0; ks < 2; ++ks) {                                          \
      const int ch = ks * 4 + grp;                                            \
      bf16x8 av[2], bg[2], bu[2];                                             \
      _Pragma("unroll")                                                       \
      for (int m = 0; m < 2; ++m) {                                           \
        const int r = wr + m * 16 + lrow;                                     \
        av[m] = *(const bf16x8*)&sA[(ab_) * 8192 + r * 64 + ((ch ^ (r & 7)) << 3)]; \
      }                                                                       \
      _Pragma("unroll")                                                       \
      for (int n = 0; n < 2; ++n) {                                           \
        const int r = wc + n * 16 + lrow;                                     \
        const int so = r * 64 + ((ch ^ (r & 7)) << 3);                        \
        bg[n] = *(const bf16x8*)&sBg[(bo_) + so];                             \
        bu[n] = *(const bf16x8*)&sBu[(bo_) + so];                             \
      }                                                                       \
      _Pragma("unroll")                                                       \
      for (int m = 0; m < 2; ++m)                                             \
        _Pragma("unroll")                                                     \
        for (int n = 0; n < 2; ++n) {                                         \
          ag[m][n] = __builtin_amdgcn_mfma_f32_16x16x32_bf16(av[m], bg[n], ag[m][n], 0, 0, 0); \
          au[m][n] = __builtin_amdgcn_mfma_f32_16x16x32_bf16(av[m], bu[n], au[m][n], 0, 0, 0); \
        }                                                                     \
    }                                                                         \
  } while (0)

  // prologue: A(0),B(0),B(1); vmcnt(2) leaves B(1) in flight
  ISSUE_A(0, 0);
  ISSUE_B(0, 0);
  SBAR0();
  ISSUE_B(64, 4096);
  SBAR0();
  WAIT_VM(2);
  __builtin_amdgcn_s_barrier();

  int bb0 = 0, bb1 = 4096, bb2 = 8192;
  for (int k = 0; k < 14; ++k) {       // 16 K-steps
    ISSUE_A((k + 1) * 64, (k + 1) & 1);
    SBAR0();
    ISSUE_B((k + 2) * 64, bb2);
    SBAR0();
    COMPUTE(k & 1, bb0);
    WAIT_VM(2);                        // A(k+1)+B(k+1) done; B(k+2) in flight
    __builtin_amdgcn_s_barrier();
    int tmp = bb0; bb0 = bb1; bb1 = bb2; bb2 = tmp;
  }
  ISSUE_A(15 * 64, 1);
  SBAR0();
  COMPUTE(0, bb0);
  WAIT_VM(0);
  __builtin_amdgcn_s_barrier();
  { int tmp = bb0; bb0 = bb1; bb1 = bb2; bb2 = tmp; }
  COMPUTE(1, bb0);
#undef ISSUE_A
#undef ISSUE_B
#undef COMPUTE

  // SwiGLU epilogue (C/D: col=lane&15, row=grp*4+i)
#pragma unroll
  for (int m = 0; m < 2; ++m) {
#pragma unroll
    for (int i = 0; i < 4; ++i) {
      const int rl = wr + m * 16 + grp * 4 + i;
      if (rl >= mguard) continue;
      bf16* orow = hbase + (size_t)rl * hstride;
#pragma unroll
      for (int n = 0; n < 2; ++n) {
        const float g = ag[m][n][i];
        const float u = au[m][n][i];
        orow[wc + n * 16 + lrow] = (bf16)(g * u * __builtin_amdgcn_rcpf(1.f + __expf(-g)));
      }
    }
  }
}

// ================= DOWN GEMM, 512 threads (8 waves), BK=64 ====================
// Tile 128m x 128n. A 2-buf, B 3-buf (2-ahead), vmcnt(2). Waves 4m x 2n (32x64).
__global__ __launch_bounds__(512, 2)
void dn9(const bf16* __restrict__ h_exp,
         const bf16* __restrict__ h_sh,
         const bf16* __restrict__ dwb,    // [E][1024][1024]
         const bf16* __restrict__ sdwb,   // [1024][2048]
         const float* __restrict__ entry_gate,
         bf16* __restrict__ out_e,
         float* __restrict__ out,
         const int* __restrict__ counts,
         const int* __restrict__ offsets,
         const int* __restrict__ tab128,
         const int* __restrict__ ntiles) {
  __shared__ __align__(16) bf16 sA[2 * 8192];    // 2 x 128x64 (32 KB)
  __shared__ __align__(16) bf16 sB[3 * 8192];    // 3 x 128x64 (48 KB) -> 80 KB

  const int bid = xcd_swz(blockIdx.x, DN_NWG);
  const int t = threadIdx.x;
  const bool is_exp = bid < DN_EXP_BLOCKS;
  const int wid = t >> 6, lane = t & 63;

  int n0, mguard, K, rowbase, NK;
  const bf16* Ab;
  const bf16* Bb;

  if (is_exp) {
    const int slot = bid >> 3;
    if (slot >= ntiles[0]) return;
    const int packed = tab128[slot];
    const int e = packed >> 16;
    const int m0 = packed & 0xffff;
    const int cnt = counts[e];
    n0 = (bid & 7) * 128;
    mguard = cnt - m0;
    K = HDIM; NK = HDIM / 64;
    rowbase = offsets[e] + m0;
    Ab = h_exp;
    Bb = dwb + (size_t)e * CDIM * HDIM + (size_t)n0 * HDIM;
  } else {
    const int sid = bid - DN_EXP_BLOCKS;
    const int m0 = (sid >> 3) * 128;
    n0 = (sid & 7) * 128;
    mguard = 128;
    K = SDIM; NK = SDIM / 64;
    rowbase = m0;
    Ab = h_sh;
    Bb = sdwb + (size_t)n0 * SDIM;
  }

  const int arow = t >> 3;
  const int sc = (t & 7) ^ (arow & 7);
  const bf16* asrc[2];
#pragma unroll
  for (int i = 0; i < 2; ++i) {
    int rg = rowbase + i * 64 + arow;
    if (is_exp && rg > N_TOK * TOPK - 1) rg = N_TOK * TOPK - 1;
    asrc[i] = Ab + (size_t)rg * K + sc * 8;
  }
  const bf16* bsrc[2];
#pragma unroll
  for (int i = 0; i < 2; ++i)
    bsrc[i] = Bb + (size_t)(i * 64 + arow) * K + sc * 8;
  const int adst = t * 8;

#define ISSUE_A(k_, ab_)                                                      \
  do {                                                                        \
    _Pragma("unroll")                                                         \
    for (int i = 0; i < 2; ++i)                                               \
      gload16(asrc[i] + (k_), &sA[(ab_) * 8192 + i * 4096 + adst]);           \
  } while (0)
#define ISSUE_B(k_, bo_)                                                      \
  do {                                                                        \
    _Pragma("unroll")                                                         \
    for (int i = 0; i < 2; ++i)                                               \
      gload16(bsrc[i] + (k_), &sB[(bo_) + i * 4096 + adst]);                  \
  } while (0)

  const int wr = (wid >> 1) * 32, wc = (wid & 1) * 64;
  const int lrow = lane & 15, grp = lane >> 4;

  f32x4 acc[2][4];
#pragma unroll
  for (int m = 0; m < 2; ++m)
#pragma unroll
    for (int n = 0; n < 4; ++n)
#pragma unroll
      for (int i = 0; i < 4; ++i) acc[m][n][i] = 0.f;

#define COMPUTE(ab_, bo_)                                                     \
  do {                                                                        \
    _Pragma("unroll")                                                         \
    for (int ks = 0; ks < 2; ++ks) {                                          \
      const int ch = ks * 4 + grp;                                            \
      bf16x8 av[2], bv[4];                                                    \
      _Pragma("unroll")                                                       \
      for (int m = 0; m < 2; ++m) {                                           \
        const int r = wr + m * 16 + lrow;                                     \
        av[m] = *(const bf16x8*)&sA[(ab_) * 8192 + r * 64 + ((ch ^ (r & 7)) << 3)]; \
      }                                                                       \
      _Pragma("unroll")                                                       \
      for (int n = 0; n < 4; ++n) {                                           \
        const int r = wc + n * 16 + lrow;                                     \
        bv[n] = *(const bf16x8*)&sB[(bo_) + r * 64 + ((ch ^ (r & 7)) << 3)];  \
      }                                                                       \
      _Pragma("unroll")                                                       \
      for (int m = 0; m < 2; ++m)                                             \
        _Pragma("unroll")                                                     \
        for (int n = 0; n < 4; ++n)                                           \
          acc[m][n] = __builtin_amdgcn_mfma_f32_16x16x32_bf16(av[m], bv[n], acc[m][n], 0, 0, 0); \
    }                                                                         \
  } while (0)

  ISSUE_A(0, 0);
  ISSUE_B(0, 0);
  SBAR0();
  ISSUE_B(64, 8192);
  SBAR0();
  WAIT_VM(2);
  __builtin_amdgcn_s_barrier();

  int bb0 = 0, bb1 = 8192, bb2 = 16384;
  for (int k = 0; k < NK - 2; ++k) {
    ISSUE_A((k + 1) * 64, (k + 1) & 1);
    SBAR0();
    ISSUE_B((k + 2) * 64, bb2);
    SBAR0();
    COMPUTE(k & 1, bb0);
    WAIT_VM(2);
    __builtin_amdgcn_s_barrier();
    int tmp = bb0; bb0 = bb1; bb1 = bb2; bb2 = tmp;
  }
  ISSUE_A((NK - 1) * 64, (NK - 1) & 1);
  SBAR0();
  COMPUTE((NK - 2) & 1, bb0);
  WAIT_VM(0);
  __builtin_amdgcn_s_barrier();
  { int tmp = bb0; bb0 = bb1; bb1 = bb2; bb2 = tmp; }
  COMPUTE((NK - 1) & 1, bb0);
#undef ISSUE_A
#undef ISSUE_B
#undef COMPUTE

#pragma unroll
  for (int m = 0; m < 2; ++m) {
#pragma unroll
    for (int i = 0; i < 4; ++i) {
      const int rl = wr + m * 16 + grp * 4 + i;
      if (rl >= mguard) continue;
      if (is_exp) {
        const int row = rowbase + rl;
        const float scl = entry_gate[row];
        bf16* orow = out_e + (size_t)row * CDIM + n0;
#pragma unroll
        for (int n = 0; n < 4; ++n)
          orow[wc + n * 16 + lrow] = (bf16)(acc[m][n][i] * scl);
      } else {
        float* orow = out + (size_t)(rowbase + rl) * CDIM + n0;
#pragma unroll
        for (int n = 0; n < 4; ++n)
          orow[wc + n * 16 + lrow] = acc[m][n][i];
      }
    }
  }
}

// ---------------- combine ----------------
__global__ void combine_kernel(float* __restrict__ out,
                               const bf16* __restrict__ out_e,
                               const int* __restrict__ entry_pos) {
  int tid = blockIdx.x * blockDim.x + threadIdx.x;
  int n = tid >> 8;
  int c4 = tid & 255;
  int p0 = entry_pos[2 * n];
  int p1 = entry_pos[2 * n + 1];
  float4 v = ((const float4*)out)[tid];
  ushort4 a = *(const ushort4*)((const u16*)out_e + (size_t)p0 * CDIM + c4 * 4);
  ushort4 b = *(const ushort4*)((const u16*)out_e + (size_t)p1 * CDIM + c4 * 4);
  v.x += fromb(a.x) + fromb(b.x);
  v.y += fromb(a.y) + fromb(b.y);
  v.z += fromb(a.z) + fromb(b.z);
  v.w += fromb(a.w) + fromb(b.w);
  ((float4*)out)[tid] = v;
}

extern "C" void kernel_launch(void* const* d_in, const int* in_sizes, int n_in,
                              void* d_out, int out_size, void* d_ws, size_t ws_size,
                              hipStream_t stream) {
  const float* x   = (const float*)d_in[0];
  const float* rw  = (const float*)d_in[1];
  const float* guw = (const float*)d_in[2];
  const float* dw  = (const float*)d_in[3];
  const float* sgw = (const float*)d_in[4];
  const float* suw = (const float*)d_in[5];
  const float* sdw = (const float*)d_in[6];
  float* out = (float*)d_out;
  char* ws = (char*)d_ws;
  const size_t MB = 1048576;

  int*   sel         = (int*)(ws + 0);
  float* gatew       = (float*)(ws + 16384);
  int*   counts      = (int*)(ws + 32768);
  int*   offsets     = (int*)(ws + 32832);
  int*   ntiles      = (int*)(ws + 32960);
  int*   tab128      = (int*)(ws + 33024);
  int*   entry_token = (int*)(ws + 33664);
  float* entry_gate  = (float*)(ws + 50048);
  int*   entry_pos   = (int*)(ws + 66432);

  bf16* xb    = (bf16*)(ws + 82816);                 // 4 MB
  bf16* h_exp = (bf16*)(ws + 82816 + 4 * MB);        // 8 MB
  bf16* h_sh  = (bf16*)(ws + 82816 + 12 * MB);       // 8 MB
  bf16* sgw_b = (bf16*)(ws + 82816 + 20 * MB);       // 4 MB
  bf16* suw_b = (bf16*)(ws + 82816 + 24 * MB);       // 4 MB
  bf16* Wbig  = (bf16*)(ws + 82816 + 28 * MB);       // 64 MB: guw_b, then dw_b
  bf16* sdw_b = (bf16*)(ws + 82816 + 92 * MB);       // 4 MB
  bf16* out_e = sgw_b;                               // alias (dead after gu9)

  // routing + fused x conversion
  router_kernel<<<N_TOK, 64, 0, stream>>>(x, rw, xb, sel, gatew);
  scan_scatter<<<1, 256, 0, stream>>>(sel, gatew, counts, offsets, tab128,
                                      ntiles, entry_token, entry_gate, entry_pos);

  // canonicalize weights
  convert_t<<<dim3(32, 16, NEXP), 256, 0, stream>>>(guw, Wbig, CDIM, 2 * HDIM);
  convert_small3<<<3072, 256, 0, stream>>>(sgw, suw, sdw, sgw_b, suw_b, sdw_b);

  // gate+up + SwiGLU (expert + shared)
  gu9<<<GU_NWG, 512, 0, stream>>>(xb, Wbig, sgw_b, suw_b, h_exp, h_sh,
                                  counts, offsets, entry_token, tab128, ntiles);

  // canonicalize dn-side expert weights (into Wbig, freed by gu9)
  convert_t<<<dim3(16, 16, NEXP), 256, 0, stream>>>(dw, Wbig, HDIM, CDIM);

  // down (expert + shared)
  dn9<<<DN_NWG, 512, 0, stream>>>(h_exp, h_sh, Wbig, sdw_b, entry_gate, out_e, out,
                                  counts, offsets, tab128, ntiles);

  // add gated expert contributions
  combine_kernel<<<(N_TOK * CDIM / 4) / 256, 256, 0, stream>>>(out, out_e, entry_pos);
}

// Round 14
// 159.905 us; speedup vs baseline: 1.2668x; 1.1130x over previous
//
#include <hip/hip_runtime.h>
#include <cstdint>

#define N_TOK 2048
#define CDIM  1024
#define NEXP  16
#define TOPK  2
#define HDIM  1024
#define SDIM  2048
#define ESLOT 48
#define GU_EXP_BLOCKS (ESLOT * 16)              // 768
#define GU_SH_BLOCKS  (16 * 32)                 // 512
#define GU_NWG (GU_EXP_BLOCKS + GU_SH_BLOCKS)   // 1280 (GEMM portion)
#define DW_CONV_BLOCKS 2048                     // 4096 dw tiles, 2/block
#define GU9X_NWG (GU_NWG + DW_CONV_BLOCKS)      // 3328
#define DN_EXP_BLOCKS (ESLOT * 8)               // 384
#define DN_SH_BLOCKS  (16 * 8)                  // 128
#define DN_NWG (DN_EXP_BLOCKS + DN_SH_BLOCKS)   // 512
#define PREP_GUW_TILES 8192                     // 32n x 16k x 16e
#define PREP_NWG (1 + PREP_GUW_TILES + 3072)    // 11265

typedef __bf16 bf16;
typedef __bf16 bf16x8 __attribute__((ext_vector_type(8)));
typedef float  f32x4  __attribute__((ext_vector_type(4)));
typedef unsigned int u32;
typedef unsigned short u16;

typedef __attribute__((address_space(3))) uint32_t lds_u32_t;
typedef __attribute__((address_space(1))) uint32_t glb_u32_t;

__device__ __forceinline__ void gload16(const void* g, void* l) {
  __builtin_amdgcn_global_load_lds((const glb_u32_t*)(uintptr_t)g,
                                   (lds_u32_t*)(uintptr_t)l, 16, 0, 0);
}
__device__ __forceinline__ float fromb(u16 s) {
  union { float f; u32 u; } z; z.u = ((u32)s) << 16; return z.f;
}
__device__ __forceinline__ int xcd_swz(int bid, int nwg) {
  return (bid & 7) * (nwg >> 3) + (bid >> 3);
}
#define SBAR0() __builtin_amdgcn_sched_barrier(0)
#define WAIT_VM(N) do { asm volatile("s_waitcnt vmcnt(" #N ")" ::: "memory"); \
                        SBAR0(); } while (0)

// transpose-convert one 64x64 tile: src [K][N] fp32 -> dst [N][K] bf16
__device__ __forceinline__ void conv_tile(const float* __restrict__ s,
                                          bf16* __restrict__ d,
                                          int K, int N, int k0, int n0,
                                          int t, float* ld) {
  const int kk = t >> 4, c4 = (t & 15) * 4;
#pragma unroll
  for (int q = 0; q < 4; ++q) {
    float4 f = *(const float4*)(s + (size_t)(k0 + kk + q * 16) * N + n0 + c4);
    float* lp = &ld[(kk + q * 16) * 68 + c4];
    lp[0] = f.x; lp[1] = f.y; lp[2] = f.z; lp[3] = f.w;
  }
  __syncthreads();
  const int nn = t >> 2, kc = (t & 3) * 16;
  bf16x8 v0, v1;
#pragma unroll
  for (int j = 0; j < 8; ++j) {
    v0[j] = (bf16)ld[(kc + j) * 68 + nn];
    v1[j] = (bf16)ld[(kc + 8 + j) * 68 + nn];
  }
  bf16* dp = d + (size_t)(n0 + nn) * K + k0 + kc;
  *(bf16x8*)dp = v0;
  *(bf16x8*)(dp + 8) = v1;
}

// ---------------- router (4 tokens/block, fused x->bf16) ----------------
__global__ __launch_bounds__(256)
void router_kernel(const float* __restrict__ x,
                   const float* __restrict__ rw,
                   bf16* __restrict__ xb,
                   int* __restrict__ sel,
                   float* __restrict__ gatew) {
  int n = blockIdx.x * 4 + (threadIdx.x >> 6);
  int lane = threadIdx.x & 63;
  const float* xr = x + (size_t)n * CDIM;
  float xv[16];
#pragma unroll
  for (int q = 0; q < 4; ++q) {
    float4 f = *(const float4*)(xr + lane * 16 + q * 4);
    xv[q * 4 + 0] = f.x; xv[q * 4 + 1] = f.y; xv[q * 4 + 2] = f.z; xv[q * 4 + 3] = f.w;
  }
  bf16x8 v0, v1;
#pragma unroll
  for (int j = 0; j < 8; ++j) { v0[j] = (bf16)xv[j]; v1[j] = (bf16)xv[8 + j]; }
  bf16* xo = xb + (size_t)n * CDIM + lane * 16;
  *(bf16x8*)xo = v0;
  *(bf16x8*)(xo + 8) = v1;
  float acc[NEXP];
#pragma unroll
  for (int e = 0; e < NEXP; ++e) {
    float a = 0.f;
    const float* rwe = rw + e * CDIM + lane * 16;
#pragma unroll
    for (int j = 0; j < 16; ++j) a += xv[j] * rwe[j];
    acc[e] = a;
  }
#pragma unroll
  for (int off = 32; off > 0; off >>= 1) {
#pragma unroll
    for (int e = 0; e < NEXP; ++e) acc[e] += __shfl_xor(acc[e], off, 64);
  }
  if (lane == 0) {
    int i0 = 0; float v0_ = acc[0];
#pragma unroll
    for (int e = 1; e < NEXP; ++e) if (acc[e] > v0_) { v0_ = acc[e]; i0 = e; }
    int i1 = (i0 == 0) ? 1 : 0; float v1_ = acc[i1];
#pragma unroll
    for (int e = 0; e < NEXP; ++e) if (e != i0 && acc[e] > v1_) { v1_ = acc[e]; i1 = e; }
    sel[2 * n] = i0; sel[2 * n + 1] = i1;
    gatew[2 * n]     = 1.f / (1.f + expf(-v0_));
    gatew[2 * n + 1] = 1.f / (1.f + expf(-v1_));
  }
}

// ---------------- prep: guw transpose-convert + small converts + scan ---------
__global__ __launch_bounds__(256)
void prep_kernel(const float* __restrict__ guw,
                 const float* __restrict__ sgw,
                 const float* __restrict__ suw,
                 const float* __restrict__ sdw,
                 bf16* __restrict__ guw_b,
                 bf16* __restrict__ sgw_b,
                 bf16* __restrict__ suw_b,
                 bf16* __restrict__ sdw_b,
                 const int* __restrict__ sel,
                 const float* __restrict__ gatew,
                 int* __restrict__ counts,
                 int* __restrict__ offsets,
                 int* __restrict__ tab128,
                 int* __restrict__ ntiles,
                 int* __restrict__ entry_token,
                 float* __restrict__ entry_gate,
                 int* __restrict__ entry_pos) {
  __shared__ __align__(16) float ld[64 * 68];
  const int b = blockIdx.x;
  const int t = threadIdx.x;
  if (b == 0) {
    int* hist = (int*)ld;
    int* cur = hist + NEXP;
    if (t < NEXP) hist[t] = 0;
    __syncthreads();
    for (int i = t; i < N_TOK * TOPK; i += 256) atomicAdd(&hist[sel[i]], 1);
    __syncthreads();
    if (t == 0) {
      int s = 0, a = 0;
      for (int e = 0; e < NEXP; ++e) {
        int c = hist[e];
        counts[e] = c; offsets[e] = s; cur[e] = s;
        for (int m0 = 0; m0 < c; m0 += 128) tab128[a++] = (e << 16) | m0;
        s += c;
      }
      ntiles[0] = a;
    }
    __syncthreads();
    for (int i = t; i < N_TOK * TOPK; i += 256) {
      int e = sel[i];
      int pos = atomicAdd(&cur[e], 1);
      entry_token[pos] = i >> 1;
      entry_gate[pos] = gatew[i];
      entry_pos[i] = pos;
    }
    return;
  }
  if (b <= PREP_GUW_TILES) {
    const int idx = b - 1;
    const int e = idx >> 9;           // 512 tiles/expert (32n x 16k)
    const int rem = idx & 511;
    const int n0 = (rem & 31) << 6;
    const int k0 = (rem >> 5) << 6;
    conv_tile(guw + (size_t)e * CDIM * 2 * HDIM,
              guw_b + (size_t)e * 2 * HDIM * CDIM,
              CDIM, 2 * HDIM, k0, n0, t, ld);
    return;
  }
  const int b2 = b - 1 - PREP_GUW_TILES;   // 0..3071
  const float* s; bf16* d;
  if (b2 < 1024)      { s = sgw; d = sgw_b; }
  else if (b2 < 2048) { s = suw; d = suw_b; }
  else                { s = sdw; d = sdw_b; }
  int i = ((b2 & 1023) * 256 + t) * 8;
  float4 f0 = *(const float4*)(s + i);
  float4 f1 = *(const float4*)(s + i + 4);
  bf16x8 v;
  v[0]=(bf16)f0.x; v[1]=(bf16)f0.y; v[2]=(bf16)f0.z; v[3]=(bf16)f0.w;
  v[4]=(bf16)f1.x; v[5]=(bf16)f1.y; v[6]=(bf16)f1.z; v[7]=(bf16)f1.w;
  *(bf16x8*)(d + i) = v;
}

// ================= GU GEMM (8 waves, BK=64, counted vmcnt) + dw convert =======
__global__ __launch_bounds__(512, 2)
void gu9x(const bf16* __restrict__ xb,
          const bf16* __restrict__ guwb,
          const bf16* __restrict__ sgwb,
          const bf16* __restrict__ suwb,
          bf16* __restrict__ h_exp,
          bf16* __restrict__ h_sh,
          const int* __restrict__ counts,
          const int* __restrict__ offsets,
          const int* __restrict__ entry_token,
          const int* __restrict__ tab128,
          const int* __restrict__ ntiles,
          const float* __restrict__ dw,
          bf16* __restrict__ dw_b) {
  __shared__ __align__(16) char smem[81920];
  bf16* sA  = (bf16*)smem;             // 2 x 128x64 = 32 KB
  bf16* sBg = (bf16*)(smem + 32768);   // 3 x 64x64  = 24 KB
  bf16* sBu = (bf16*)(smem + 57344);   // 24 KB

  const int t = threadIdx.x;

  // trailing blocks: dw transpose-convert, 2 tiles per block (one per 256-half)
  if (blockIdx.x >= GU_NWG) {
    const int tid2 = (blockIdx.x - GU_NWG) * 2 + (t >> 8);
    float* ld = (float*)(smem + (t >> 8) * 17408);
    const int e = tid2 >> 8;           // 256 tiles/expert (16n x 16k)
    const int rem = tid2 & 255;
    const int n0c = (rem & 15) << 6;
    const int k0c = (rem >> 4) << 6;
    conv_tile(dw + (size_t)e * HDIM * CDIM,
              dw_b + (size_t)e * CDIM * HDIM,
              HDIM, CDIM, k0c, n0c, t & 255, ld);
    return;
  }

  const int bid = xcd_swz(blockIdx.x, GU_NWG);
  const bool is_exp = bid < GU_EXP_BLOCKS;
  const int wid = t >> 6, lane = t & 63;

  int n0, mguard;
  bf16* hbase; int hstride;
  const bf16 *Bg, *Bu;
  const int arow = t >> 3;
  const int sc = (t & 7) ^ (arow & 7);
  const bf16* asrc[2];

  if (is_exp) {
    const int slot = bid >> 4;
    if (slot >= ntiles[0]) return;
    const int packed = tab128[slot];
    const int e = packed >> 16;
    const int m0 = packed & 0xffff;
    const int cnt = counts[e];
    const int base = offsets[e];
    n0 = (bid & 15) * 64;
    mguard = cnt - m0;
#pragma unroll
    for (int i = 0; i < 2; ++i) {
      int r = m0 + i * 64 + arow;
      int tok = entry_token[base + ((r < cnt) ? r : (cnt - 1))];
      asrc[i] = xb + (size_t)tok * CDIM + sc * 8;
    }
    const bf16* we = guwb + (size_t)e * (2 * HDIM) * CDIM;
    Bg = we + (size_t)n0 * CDIM;
    Bu = we + (size_t)(HDIM + n0) * CDIM;
    hbase = h_exp + (size_t)(base + m0) * HDIM + n0;
    hstride = HDIM;
  } else {
    const int sid = bid - GU_EXP_BLOCKS;
    const int m0 = (sid >> 5) * 128;
    n0 = (sid & 31) * 64;
    mguard = 128;
#pragma unroll
    for (int i = 0; i < 2; ++i)
      asrc[i] = xb + (size_t)(m0 + i * 64 + arow) * CDIM + sc * 8;
    Bg = sgwb + (size_t)n0 * CDIM;
    Bu = suwb + (size_t)n0 * CDIM;
    hbase = h_sh + (size_t)m0 * SDIM + n0;
    hstride = SDIM;
  }

  const int th = t & 255;
  bf16* bdst = (t >= 256) ? sBu : sBg;
  const bf16* Bp = (t >= 256) ? Bu : Bg;
  const bf16* bsrc[2];
#pragma unroll
  for (int i = 0; i < 2; ++i) {
    const int row = i * 32 + (th >> 3);
    const int c = (th & 7) ^ (row & 7);
    bsrc[i] = Bp + (size_t)row * CDIM + c * 8;
  }
  const int adst = t * 8;
  const int bdoff = th * 8;

#define ISSUE_A(k_, ab_)                                                      \
  do {                                                                        \
    _Pragma("unroll")                                                         \
    for (int i = 0; i < 2; ++i)                                               \
      gload16(asrc[i] + (k_), &sA[(ab_) * 8192 + i * 4096 + adst]);           \
  } while (0)
#define ISSUE_B(k_, bo_)                                                      \
  do {                                                                        \
    _Pragma("unroll")                                                         \
    for (int i = 0; i < 2; ++i)                                               \
      gload16(bsrc[i] + (k_), &bdst[(bo_) + i * 2048 + bdoff]);               \
  } while (0)

  const int wr = (wid >> 1) * 32, wc = (wid & 1) * 32;
  const int lrow = lane & 15, grp = lane >> 4;

  f32x4 ag[2][2], au[2][2];
#pragma unroll
  for (int m = 0; m < 2; ++m)
#pragma unroll
    for (int n = 0; n < 2; ++n)
#pragma unroll
      for (int i = 0; i < 4; ++i) { ag[m][n][i] = 0.f; au[m][n][i] = 0.f; }

#define COMPUTE(ab_, bo_)                                                     \
  do {                                                                        \
    _Pragma("unroll")                                                         \
    for (int ks = 0; ks < 2; ++ks) {                                          \
      const int ch = ks * 4 + grp;                                            \
      bf16x8 av[2], bg[2], bu[2];                                             \
      _Pragma("unroll")                                                       \
      for (int m = 0; m < 2; ++m) {                                           \
        const int r = wr + m * 16 + lrow;                                     \
        av[m] = *(const bf16x8*)&sA[(ab_) * 8192 + r * 64 + ((ch ^ (r & 7)) << 3)]; \
      }                                                                       \
      _Pragma("unroll")                                                       \
      for (int n = 0; n < 2; ++n) {                                           \
        const int r = wc + n * 16 + lrow;                                     \
        const int so = r * 64 + ((ch ^ (r & 7)) << 3);                        \
        bg[n] = *(const bf16x8*)&sBg[(bo_) + so];                             \
        bu[n] = *(const bf16x8*)&sBu[(bo_) + so];                             \
      }                                                                       \
      _Pragma("unroll")                                                       \
      for (int m = 0; m < 2; ++m)                                             \
        _Pragma("unroll")                                                     \
        for (int n = 0; n < 2; ++n) {                                         \
          ag[m][n] = __builtin_amdgcn_mfma_f32_16x16x32_bf16(av[m], bg[n], ag[m][n], 0, 0, 0); \
          au[m][n] = __builtin_amdgcn_mfma_f32_16x16x32_bf16(av[m], bu[n], au[m][n], 0, 0, 0); \
        }                                                                     \
    }                                                                         \
  } while (0)

  ISSUE_A(0, 0);
  ISSUE_B(0, 0);
  SBAR0();
  ISSUE_B(64, 4096);
  SBAR0();
  WAIT_VM(2);
  __builtin_amdgcn_s_barrier();

  int bb0 = 0, bb1 = 4096, bb2 = 8192;
  for (int k = 0; k < 14; ++k) {
    ISSUE_A((k + 1) * 64, (k + 1) & 1);
    SBAR0();
    ISSUE_B((k + 2) * 64, bb2);
    SBAR0();
    COMPUTE(k & 1, bb0);
    WAIT_VM(2);
    __builtin_amdgcn_s_barrier();
    int tmp = bb0; bb0 = bb1; bb1 = bb2; bb2 = tmp;
  }
  ISSUE_A(15 * 64, 1);
  SBAR0();
  COMPUTE(0, bb0);
  WAIT_VM(0);
  __builtin_amdgcn_s_barrier();
  { int tmp = bb0; bb0 = bb1; bb1 = bb2; bb2 = tmp; }
  COMPUTE(1, bb0);
#undef ISSUE_A
#undef ISSUE_B
#undef COMPUTE

#pragma unroll
  for (int m = 0; m < 2; ++m) {
#pragma unroll
    for (int i = 0; i < 4; ++i) {
      const int rl = wr + m * 16 + grp * 4 + i;
      if (rl >= mguard) continue;
      bf16* orow = hbase + (size_t)rl * hstride;
#pragma unroll
      for (int n = 0; n < 2; ++n) {
        const float g = ag[m][n][i];
        const float u = au[m][n][i];
        orow[wc + n * 16 + lrow] = (bf16)(g * u * __builtin_amdgcn_rcpf(1.f + __expf(-g)));
      }
    }
  }
}

// ================= DOWN GEMM (8 waves, BK=64, counted vmcnt) ==================
__global__ __launch_bounds__(512, 2)
void dn9(const bf16* __restrict__ h_exp,
         const bf16* __restrict__ h_sh,
         const bf16* __restrict__ dwb,
         const bf16* __restrict__ sdwb,
         const float* __restrict__ entry_gate,
         bf16* __restrict__ out_e,
         float* __restrict__ out,
         const int* __restrict__ counts,
         const int* __restrict__ offsets,
         const int* __restrict__ tab128,
         const int* __restrict__ ntiles) {
  __shared__ __align__(16) bf16 sA[2 * 8192];
  __shared__ __align__(16) bf16 sB[3 * 8192];

  const int bid = xcd_swz(blockIdx.x, DN_NWG);
  const int t = threadIdx.x;
  const bool is_exp = bid < DN_EXP_BLOCKS;
  const int wid = t >> 6, lane = t & 63;

  int n0, mguard, K, rowbase, NK;
  const bf16* Ab;
  const bf16* Bb;

  if (is_exp) {
    const int slot = bid >> 3;
    if (slot >= ntiles[0]) return;
    const int packed = tab128[slot];
    const int e = packed >> 16;
    const int m0 = packed & 0xffff;
    const int cnt = counts[e];
    n0 = (bid & 7) * 128;
    mguard = cnt - m0;
    K = HDIM; NK = HDIM / 64;
    rowbase = offsets[e] + m0;
    Ab = h_exp;
    Bb = dwb + (size_t)e * CDIM * HDIM + (size_t)n0 * HDIM;
  } else {
    const int sid = bid - DN_EXP_BLOCKS;
    const int m0 = (sid >> 3) * 128;
    n0 = (sid & 7) * 128;
    mguard = 128;
    K = SDIM; NK = SDIM / 64;
    rowbase = m0;
    Ab = h_sh;
    Bb = sdwb + (size_t)n0 * SDIM;
  }

  const int arow = t >> 3;
  const int sc = (t & 7) ^ (arow & 7);
  const bf16* asrc[2];
#pragma unroll
  for (int i = 0; i < 2; ++i) {
    int rg = rowbase + i * 64 + arow;
    if (is_exp && rg > N_TOK * TOPK - 1) rg = N_TOK * TOPK - 1;
    asrc[i] = Ab + (size_t)rg * K + sc * 8;
  }
  const bf16* bsrc[2];
#pragma unroll
  for (int i = 0; i < 2; ++i)
    bsrc[i] = Bb + (size_t)(i * 64 + arow) * K + sc * 8;
  const int adst = t * 8;

#define ISSUE_A(k_, ab_)                                                      \
  do {                                                                        \
    _Pragma("unroll")                                                         \
    for (int i = 0; i < 2; ++i)                                               \
      gload16(asrc[i] + (k_), &sA[(ab_) * 8192 + i * 4096 + adst]);           \
  } while (0)
#define ISSUE_B(k_, bo_)                                                      \
  do {                                                                        \
    _Pragma("unroll")                                                         \
    for (int i = 0; i < 2; ++i)                                               \
      gload16(bsrc[i] + (k_), &sB[(bo_) + i * 4096 + adst]);                  \
  } while (0)

  const int wr = (wid >> 1) * 32, wc = (wid & 1) * 64;
  const int lrow = lane & 15, grp = lane >> 4;

  f32x4 acc[2][4];
#pragma unroll
  for (int m = 0; m < 2; ++m)
#pragma unroll
    for (int n = 0; n < 4; ++n)
#pragma unroll
      for (int i = 0; i < 4; ++i) acc[m][n][i] = 0.f;

#define COMPUTE(ab_, bo_)                                                     \
  do {                                                                        \
    _Pragma("unroll")                                                         \
    for (int ks = 0; ks < 2; ++ks) {                                          \
      const int ch = ks * 4 + grp;                                            \
      bf16x8 av[2], bv[4];                                                    \
      _Pragma("unroll")                                                       \
      for (int m = 0; m < 2; ++m) {                                           \
        const int r = wr + m * 16 + lrow;                                     \
        av[m] = *(const bf16x8*)&sA[(ab_) * 8192 + r * 64 + ((ch ^ (r & 7)) << 3)]; \
      }                                                                       \
      _Pragma("unroll")                                                       \
      for (int n = 0; n < 4; ++n) {                                           \
        const int r = wc + n * 16 + lrow;                                     \
        bv[n] = *(const bf16x8*)&sB[(bo_) + r * 64 + ((ch ^ (r & 7)) << 3)];  \
      }                                                                       \
      _Pragma("unroll")                                                       \
      for (int m = 0; m < 2; ++m)                                             \
        _Pragma("unroll")                                                     \
        for (int n = 0; n < 4; ++n)                                           \
          acc[m][n] = __builtin_amdgcn_mfma_f32_16x16x32_bf16(av[m], bv[n], acc[m][n], 0, 0, 0); \
    }                                                                         \
  } while (0)

  ISSUE_A(0, 0);
  ISSUE_B(0, 0);
  SBAR0();
  ISSUE_B(64, 8192);
  SBAR0();
  WAIT_VM(2);
  __builtin_amdgcn_s_barrier();

  int bb0 = 0, bb1 = 8192, bb2 = 16384;
  for (int k = 0; k < NK - 2; ++k) {
    ISSUE_A((k + 1) * 64, (k + 1) & 1);
    SBAR0();
    ISSUE_B((k + 2) * 64, bb2);
    SBAR0();
    COMPUTE(k & 1, bb0);
    WAIT_VM(2);
    __builtin_amdgcn_s_barrier();
    int tmp = bb0; bb0 = bb1; bb1 = bb2; bb2 = tmp;
  }
  ISSUE_A((NK - 1) * 64, (NK - 1) & 1);
  SBAR0();
  COMPUTE((NK - 2) & 1, bb0);
  WAIT_VM(0);
  __builtin_amdgcn_s_barrier();
  { int tmp = bb0; bb0 = bb1; bb1 = bb2; bb2 = tmp; }
  COMPUTE((NK - 1) & 1, bb0);
#undef ISSUE_A
#undef ISSUE_B
#undef COMPUTE

#pragma unroll
  for (int m = 0; m < 2; ++m) {
#pragma unroll
    for (int i = 0; i < 4; ++i) {
      const int rl = wr + m * 16 + grp * 4 + i;
      if (rl >= mguard) continue;
      if (is_exp) {
        const int row = rowbase + rl;
        const float scl = entry_gate[row];
        bf16* orow = out_e + (size_t)row * CDIM + n0;
#pragma unroll
        for (int n = 0; n < 4; ++n)
          orow[wc + n * 16 + lrow] = (bf16)(acc[m][n][i] * scl);
      } else {
        float* orow = out + (size_t)(rowbase + rl) * CDIM + n0;
#pragma unroll
        for (int n = 0; n < 4; ++n)
          orow[wc + n * 16 + lrow] = acc[m][n][i];
      }
    }
  }
}

// ---------------- combine ----------------
__global__ void combine_kernel(float* __restrict__ out,
                               const bf16* __restrict__ out_e,
                               const int* __restrict__ entry_pos) {
  int tid = blockIdx.x * blockDim.x + threadIdx.x;
  int n = tid >> 8;
  int c4 = tid & 255;
  int p0 = entry_pos[2 * n];
  int p1 = entry_pos[2 * n + 1];
  float4 v = ((const float4*)out)[tid];
  ushort4 a = *(const ushort4*)((const u16*)out_e + (size_t)p0 * CDIM + c4 * 4);
  ushort4 b = *(const ushort4*)((const u16*)out_e + (size_t)p1 * CDIM + c4 * 4);
  v.x += fromb(a.x) + fromb(b.x);
  v.y += fromb(a.y) + fromb(b.y);
  v.z += fromb(a.z) + fromb(b.z);
  v.w += fromb(a.w) + fromb(b.w);
  ((float4*)out)[tid] = v;
}

extern "C" void kernel_launch(void* const* d_in, const int* in_sizes, int n_in,
                              void* d_out, int out_size, void* d_ws, size_t ws_size,
                              hipStream_t stream) {
  const float* x   = (const float*)d_in[0];
  const float* rw  = (const float*)d_in[1];
  const float* guw = (const float*)d_in[2];
  const float* dw  = (const float*)d_in[3];
  const float* sgw = (const float*)d_in[4];
  const float* suw = (const float*)d_in[5];
  const float* sdw = (const float*)d_in[6];
  float* out = (float*)d_out;
  char* ws = (char*)d_ws;
  const size_t MB = 1048576;

  int*   sel         = (int*)(ws + 0);
  float* gatew       = (float*)(ws + 16384);
  int*   counts      = (int*)(ws + 32768);
  int*   offsets     = (int*)(ws + 32832);
  int*   ntiles      = (int*)(ws + 32960);
  int*   tab128      = (int*)(ws + 33024);
  int*   entry_token = (int*)(ws + 33664);
  float* entry_gate  = (float*)(ws + 50048);
  int*   entry_pos   = (int*)(ws + 66432);

  bf16* xb    = (bf16*)(ws + 82816);                 // 4 MB
  bf16* h_exp = (bf16*)(ws + 82816 + 4 * MB);        // 8 MB
  bf16* h_sh  = (bf16*)(ws + 82816 + 12 * MB);       // 8 MB
  bf16* sgw_b = (bf16*)(ws + 82816 + 20 * MB);       // 4 MB
  bf16* suw_b = (bf16*)(ws + 82816 + 24 * MB);       // 4 MB
  bf16* guw_b = (bf16*)(ws + 82816 + 28 * MB);       // 64 MB
  bf16* dw_b  = (bf16*)(ws + 82816 + 92 * MB);       // 32 MB (no longer aliased)
  bf16* sdw_b = (bf16*)(ws + 82816 + 124 * MB);      // 4 MB (peak ~128 MB)
  bf16* out_e = sgw_b;                               // alias (dead after gu9x)

  // 1) routing + fused x conversion
  router_kernel<<<N_TOK / 4, 256, 0, stream>>>(x, rw, xb, sel, gatew);

  // 2) guw transpose-convert + small converts + scan/scatter (one launch)
  prep_kernel<<<PREP_NWG, 256, 0, stream>>>(guw, sgw, suw, sdw,
                                            guw_b, sgw_b, suw_b, sdw_b,
                                            sel, gatew, counts, offsets, tab128,
                                            ntiles, entry_token, entry_gate, entry_pos);

  // 3) gate+up GEMM + SwiGLU, with dw transpose-convert in trailing blocks
  gu9x<<<GU9X_NWG, 512, 0, stream>>>(xb, guw_b, sgw_b, suw_b, h_exp, h_sh,
                                     counts, offsets, entry_token, tab128, ntiles,
                                     dw, dw_b);

  // 4) down GEMM (expert + shared)
  dn9<<<DN_NWG, 512, 0, stream>>>(h_exp, h_sh, dw_b, sdw_b, entry_gate, out_e, out,
                                  counts, offsets, tab128, ntiles);

  // 5) add gated expert contributions
  combine_kernel<<<(N_TOK * CDIM / 4) / 256, 256, 0, stream>>>(out, out_e, entry_pos);
}